// Round 2
// baseline (838.267 us; speedup 1.0000x reference)
//
#include <hip/hip_runtime.h>
#include <stdint.h>

typedef __bf16 bf16x8 __attribute__((ext_vector_type(8)));
typedef float  f32x4  __attribute__((ext_vector_type(4)));

// ---------------- gather / copy (fp32 rows, uint4 = 4 floats) ----------------
__global__ void k_unpool(const uint4* __restrict__ xin, const int* __restrict__ up,
                         uint4* __restrict__ xout, int N, int rowU4) {
  int i = blockIdx.x * 256 + threadIdx.x;
  if (i >= N * rowU4) return;
  int n = i / rowU4, j = i - n * rowU4;
  xout[i] = xin[(size_t)up[n] * rowU4 + j];
}

__global__ void k_skip(const uint4* __restrict__ skip, uint4* __restrict__ xcat,
                       int N, int rowU4, int dstStrideU4, int dstOffU4) {
  int i = blockIdx.x * 256 + threadIdx.x;
  if (i >= N * rowU4) return;
  int n = i / rowU4, j = i - n * rowU4;
  xcat[(size_t)n * dstStrideU4 + dstOffU4 + j] = skip[i];
}

// ---------------- CSR build ----------------
__global__ void k_hist(const int* __restrict__ dst, int E, int* __restrict__ cnt) {
  int e = blockIdx.x * 256 + threadIdx.x;
  if (e < E) atomicAdd(&cnt[dst[e]], 1);
}

__global__ void k_scan(const int* __restrict__ cnt, int* __restrict__ off, int N) {
  __shared__ int wsum[16];
  __shared__ int carry_s;
  int t = threadIdx.x;
  int lane = t & 63, w = t >> 6;
  if (t == 0) carry_s = 0;
  __syncthreads();
  for (int base = 0; base < N; base += 4096) {
    int i0 = base + t * 4;
    int v0 = (i0 + 0 < N) ? cnt[i0 + 0] : 0;
    int v1 = (i0 + 1 < N) ? cnt[i0 + 1] : 0;
    int v2 = (i0 + 2 < N) ? cnt[i0 + 2] : 0;
    int v3 = (i0 + 3 < N) ? cnt[i0 + 3] : 0;
    int s = v0 + v1 + v2 + v3;
    int x = s;
    #pragma unroll
    for (int o = 1; o < 64; o <<= 1) {
      int y = __shfl_up(x, o, 64);
      if (lane >= o) x += y;
    }
    if (lane == 63) wsum[w] = x;
    __syncthreads();
    int wpre = 0, tot = 0;
    #pragma unroll
    for (int k = 0; k < 16; ++k) { int ws = wsum[k]; tot += ws; if (k < w) wpre += ws; }
    int c = carry_s;
    int excl = c + wpre + x - s;
    if (i0 + 0 < N) off[i0 + 0] = excl; excl += v0;
    if (i0 + 1 < N) off[i0 + 1] = excl; excl += v1;
    if (i0 + 2 < N) off[i0 + 2] = excl; excl += v2;
    if (i0 + 3 < N) off[i0 + 3] = excl;
    __syncthreads();
    if (t == 0) carry_s = c + tot;
    __syncthreads();
  }
  if (t == 0) off[N] = carry_s;
}

__global__ void k_place(const int* __restrict__ dst, int E, const int* __restrict__ off,
                        int* __restrict__ cur, int* __restrict__ eid) {
  int e = blockIdx.x * 256 + threadIdx.x;
  if (e >= E) return;
  int d = dst[e];
  int p = atomicAdd(&cur[d], 1);
  eid[off[d] + p] = e;
}

// ---------------- weight pre-pack (fp32 W,R -> bf16 MFMA B-fragments) ----------------
// B[cin][col], col<9*Cout: W[k9][cin][cout] (col=k9*Cout+cout); col>=9*Cout: R[cin][col-9*Cout].
// Bp element o = ((kc*CT+ct)*64 + lane)*8 + j holds B[k=kc*32+(lane>>4)*8+j][ct*16+(lane&15)].
template<int Cin, int Cout>
__global__ void k_pack(const float* __restrict__ W, const float* __restrict__ R,
                       __bf16* __restrict__ Bp) {
  constexpr int NC = 10 * Cout;
  constexpr int CT = NC / 16;
  constexpr int KP = (Cin + 31) & ~31;
  int o = blockIdx.x * 256 + threadIdx.x;
  if (o >= KP * NC) return;
  int j = o & 7;
  int lane = (o >> 3) & 63;
  int tile = o >> 9;
  int ct = tile % CT, kc = tile / CT;
  int kg = kc * 32 + ((lane >> 4) * 8) + j;   // = cin (maybe padded)
  int col = ct * 16 + (lane & 15);
  float v = 0.f;
  if (kg < Cin) {
    if (col < 9 * Cout) {
      int k9 = col / Cout, cout = col - k9 * Cout;
      v = W[(k9 * Cin + kg) * Cout + cout];
    } else {
      v = R[kg * Cout + (col - 9 * Cout)];
    }
  }
  Bp[o] = (__bf16)v;
}

// ---------------- Z = X @ B  (MFMA 16x16x32 bf16, fp32 A converted on the fly) --------
template<int Cin, int NC>
__global__ __launch_bounds__(256) void k_zgemm(const float* __restrict__ X,
                        const __bf16* __restrict__ Bp, __bf16* __restrict__ Z, int N) {
  constexpr int KP = (Cin + 31) & ~31;
  constexpr int KC = KP / 32;
  constexpr int CT = NC / 16;
  int lane = threadIdx.x & 63;
  int wave = threadIdx.x >> 6;
  int n0 = blockIdx.x * 64 + wave * 16;
  if (n0 >= N) return;
  int c15 = lane & 15, q = lane >> 4;

  bf16x8 a[KC];
  #pragma unroll
  for (int kc = 0; kc < KC; ++kc) {
    int kofs = kc * 32 + q * 8;
    if (kofs + 8 <= Cin) {
      const float* xr = X + (size_t)(n0 + c15) * Cin + kofs;
      f32x4 lo = *reinterpret_cast<const f32x4*>(xr);
      f32x4 hi = *reinterpret_cast<const f32x4*>(xr + 4);
      #pragma unroll
      for (int t = 0; t < 4; ++t) { a[kc][t] = (__bf16)lo[t]; a[kc][4 + t] = (__bf16)hi[t]; }
    } else {
      #pragma unroll
      for (int t = 0; t < 8; ++t) a[kc][t] = (__bf16)0.0f;
    }
  }

  for (int ct = 0; ct < CT; ++ct) {
    f32x4 acc = {0.f, 0.f, 0.f, 0.f};
    #pragma unroll
    for (int kc = 0; kc < KC; ++kc) {
      bf16x8 b = *reinterpret_cast<const bf16x8*>(Bp + ((size_t)(kc * CT + ct) * 64 + lane) * 8);
      acc = __builtin_amdgcn_mfma_f32_16x16x32_bf16(a[kc], b, acc, 0, 0, 0);
    }
    // C/D layout (m89-verified): col = lane&15, row = (lane>>4)*4 + reg
    __bf16* zb = Z + (size_t)n0 * NC + ct * 16 + c15;
    #pragma unroll
    for (int r = 0; r < 4; ++r) {
      zb[(size_t)(q * 4 + r) * NC] = (__bf16)acc[r];
    }
  }
}

// ------------- edge aggregation (CSR gather) + folded R-term + bias + ReLU -------------
template<int Cout>
__global__ __launch_bounds__(256) void k_econv(const int* __restrict__ src,
                        const float* __restrict__ pseudo,
                        const int* __restrict__ off, const int* __restrict__ eid,
                        const __bf16* __restrict__ Z,
                        const float* __restrict__ bias,
                        float* __restrict__ out, int N, int outStride) {
  constexpr int NC = 10 * Cout;
  int t = blockIdx.x * 256 + threadIdx.x;
  int d = t / Cout;           // Cout is a power of two
  int c = t - d * Cout;
  if (d >= N) return;
  // own-node R-term folded into Z as columns [9*Cout, 10*Cout)
  float acc = (float)Z[(size_t)d * NC + 9 * Cout + c];
  int b0 = off[d], b1 = off[d + 1];
  for (int i = b0; i < b1; ++i) {
    int e = eid[i];
    int s = src[e];
    float t0 = pseudo[2 * (size_t)e + 0];
    float t1 = pseudo[2 * (size_t)e + 1];
    float u0 = 1.f - t0;
    float wi[3] = {0.5f * u0 * u0, -t0 * t0 + t0 + 0.5f, 0.5f * t0 * t0};
    float u1 = 1.f - t1;
    float wj[3] = {0.5f * u1 * u1, -t1 * t1 + t1 + 0.5f, 0.5f * t1 * t1};
    const __bf16* zr = Z + (size_t)s * NC + c;
    float m = 0.f;
    #pragma unroll
    for (int ki = 0; ki < 3; ++ki)
      #pragma unroll
      for (int kj = 0; kj < 3; ++kj)
        m += (wi[ki] * wj[kj]) * (float)zr[(ki * 3 + kj) * Cout];
    acc += m;
  }
  acc += bias[c];
  acc = fmaxf(acc, 0.f);
  out[(size_t)d * outStride + c] = acc;
}

extern "C" void kernel_launch(void* const* d_in, const int* in_sizes, int n_in,
                              void* d_out, int out_size, void* d_ws, size_t ws_size,
                              hipStream_t stream) {
  const float* x0      = (const float*)d_in[0];
  const int*   up1     = (const int*)d_in[1];
  const int*   edge1   = (const int*)d_in[2];
  const float* pseudo1 = (const float*)d_in[3];
  const float* skip1   = (const float*)d_in[4];
  const int*   up2     = (const int*)d_in[5];
  const int*   edge2   = (const int*)d_in[6];
  const float* pseudo2 = (const float*)d_in[7];
  const float* skip2   = (const float*)d_in[8];
  const float* W1a = (const float*)d_in[9];
  const float* R1a = (const float*)d_in[10];
  const float* b1a = (const float*)d_in[11];
  const float* W2a = (const float*)d_in[12];
  const float* R2a = (const float*)d_in[13];
  const float* b2a = (const float*)d_in[14];
  const float* W1b = (const float*)d_in[15];
  const float* R1b = (const float*)d_in[16];
  const float* b1b = (const float*)d_in[17];
  const float* W2b = (const float*)d_in[18];
  const float* R2b = (const float*)d_in[19];
  const float* b2b = (const float*)d_in[20];

  const int N1 = 40000, N2 = 160000, E1 = 240000, E2 = 960000;

  char* ws = (char*)d_ws;
  __bf16* Z   = (__bf16*)(ws);                 // max(N1*320,N2*160)*2 = 51,200,000 B
  float* featA = (float*)(ws + 51200000);      // 20,480,000 B  x1[N1,64] / x2[N2,32]
  float* featB = (float*)(ws + 71680000);      // 20,480,000 B  xcat1[N1,64] / xcat2[N2,32]
  float* featC = (float*)(ws + 92160000);      // 10,240,000 B  x3[N1,32] / x6[N2,16]
  float* featD = (float*)(ws + 102400000);     //  5,120,000 B  h1[N1,32]
  int* off    = (int*)(ws + 107520000);        //  640,004 B (N2+1)
  int* cnt    = (int*)(ws + 108170000);        //  640,000 B
  int* eid    = (int*)(ws + 108810000);        //  3,840,000 B (E2)
  __bf16* BpA = (__bf16*)(ws + 112650000);     //  40,960 B (64x320)
  __bf16* BpB = (__bf16*)(ws + 112690960);     //  20,480 B (32x320)
  __bf16* BpC = (__bf16*)(ws + 112711440);     //  10,240 B (32x160)
  __bf16* BpD = (__bf16*)(ws + 112721680);     //  10,240 B (32x160, K padded from 16)

  // weight packs (tiny)
  k_pack<64, 32><<<80, 256, 0, stream>>>(W1a, R1a, BpA);   // 64*320 = 20480
  k_pack<32, 32><<<40, 256, 0, stream>>>(W2a, R2a, BpB);   // 32*320 = 10240
  k_pack<32, 16><<<20, 256, 0, stream>>>(W1b, R1b, BpC);   // 32*160 = 5120
  k_pack<16, 16><<<20, 256, 0, stream>>>(W2b, R2b, BpD);   // 32*160 = 5120

  // ---------------- level 1 ----------------
  k_unpool<<<(N1 * 16 + 255) / 256, 256, 0, stream>>>((const uint4*)x0, up1, (uint4*)featA, N1, 16);

  hipMemsetAsync(cnt, 0, N1 * 4, stream);
  k_hist<<<(E1 + 255) / 256, 256, 0, stream>>>(edge1 + E1, E1, cnt);
  k_scan<<<1, 1024, 0, stream>>>(cnt, off, N1);
  hipMemsetAsync(cnt, 0, N1 * 4, stream);
  k_place<<<(E1 + 255) / 256, 256, 0, stream>>>(edge1 + E1, E1, off, cnt, eid);

  // conv1a: x1(64) -> xcat1[:, :32]
  k_zgemm<64, 320><<<N1 / 64, 256, 0, stream>>>(featA, BpA, Z, N1);
  k_econv<32><<<N1 * 32 / 256, 256, 0, stream>>>(edge1, pseudo1, off, eid, Z, b1a, featB, N1, 64);
  k_skip<<<(N1 * 8 + 255) / 256, 256, 0, stream>>>((const uint4*)skip1, (uint4*)featB, N1, 8, 16, 8);
  // conv2a (reuses W1a,R1a,b1a): xcat1(64) -> x3(32)
  k_zgemm<64, 320><<<N1 / 64, 256, 0, stream>>>(featB, BpA, Z, N1);
  k_econv<32><<<N1 * 32 / 256, 256, 0, stream>>>(edge1, pseudo1, off, eid, Z, b1a, featC, N1, 32);
  // conv3a: x3(32) -> h1(32)
  k_zgemm<32, 320><<<N1 / 64, 256, 0, stream>>>(featC, BpB, Z, N1);
  k_econv<32><<<N1 * 32 / 256, 256, 0, stream>>>(edge1, pseudo1, off, eid, Z, b2a, featD, N1, 32);

  // ---------------- level 2 ----------------
  k_unpool<<<(N2 * 8 + 255) / 256, 256, 0, stream>>>((const uint4*)featD, up2, (uint4*)featA, N2, 8);

  hipMemsetAsync(cnt, 0, N2 * 4, stream);
  k_hist<<<(E2 + 255) / 256, 256, 0, stream>>>(edge2 + E2, E2, cnt);
  k_scan<<<1, 1024, 0, stream>>>(cnt, off, N2);
  hipMemsetAsync(cnt, 0, N2 * 4, stream);
  k_place<<<(E2 + 255) / 256, 256, 0, stream>>>(edge2 + E2, E2, off, cnt, eid);

  // conv1b: x2(32) -> xcat2[:, :16]
  k_zgemm<32, 160><<<N2 / 64, 256, 0, stream>>>(featA, BpC, Z, N2);
  k_econv<16><<<N2 * 16 / 256, 256, 0, stream>>>(edge2, pseudo2, off, eid, Z, b1b, featB, N2, 32);
  k_skip<<<(N2 * 4 + 255) / 256, 256, 0, stream>>>((const uint4*)skip2, (uint4*)featB, N2, 4, 8, 4);
  // conv2b (reuses W1b,R1b,b1b): xcat2(32) -> x6(16)
  k_zgemm<32, 160><<<N2 / 64, 256, 0, stream>>>(featB, BpC, Z, N2);
  k_econv<16><<<N2 * 16 / 256, 256, 0, stream>>>(edge2, pseudo2, off, eid, Z, b1b, featC, N2, 16);
  // conv3b: x6(16) -> out(16)
  k_zgemm<16, 160><<<N2 / 64, 256, 0, stream>>>(featC, BpD, Z, N2);
  k_econv<16><<<N2 * 16 / 256, 256, 0, stream>>>(edge2, pseudo2, off, eid, Z, b2b, (float*)d_out, N2, 16);
}

// Round 3
// 743.931 us; speedup vs baseline: 1.1268x; 1.1268x over previous
//
#include <hip/hip_runtime.h>
#include <stdint.h>

typedef __bf16 bf16x8 __attribute__((ext_vector_type(8)));
typedef float  f32x4  __attribute__((ext_vector_type(4)));

// ---------------- gather / copy (fp32 rows, uint4 = 4 floats) ----------------
__global__ void k_unpool(const uint4* __restrict__ xin, const int* __restrict__ up,
                         uint4* __restrict__ xout, int N, int rowU4) {
  int i = blockIdx.x * 256 + threadIdx.x;
  if (i >= N * rowU4) return;
  int n = i / rowU4, j = i - n * rowU4;
  xout[i] = xin[(size_t)up[n] * rowU4 + j];
}

__global__ void k_skip(const uint4* __restrict__ skip, uint4* __restrict__ xcat,
                       int N, int rowU4, int dstStrideU4, int dstOffU4) {
  int i = blockIdx.x * 256 + threadIdx.x;
  if (i >= N * rowU4) return;
  int n = i / rowU4, j = i - n * rowU4;
  xcat[(size_t)n * dstStrideU4 + dstOffU4 + j] = skip[i];
}

// ---------------- CSR build (hist + hierarchical scan + place) ----------------
__global__ void k_hist(const int* __restrict__ dst, int E, int* __restrict__ cnt) {
  int e = blockIdx.x * 256 + threadIdx.x;
  if (e < E) atomicAdd(&cnt[dst[e]], 1);
}

// stage 1: per-1024-chunk sums, 256 threads/block
__global__ void k_blocksum(const int* __restrict__ cnt, int N, int* __restrict__ bsum) {
  int b = blockIdx.x;
  int t = threadIdx.x;
  int i0 = b * 1024 + t * 4;
  int s = 0;
  if (i0 + 3 < N) {
    int4 v = *reinterpret_cast<const int4*>(cnt + i0);
    s = v.x + v.y + v.z + v.w;
  } else {
    #pragma unroll
    for (int k = 0; k < 4; ++k) if (i0 + k < N) s += cnt[i0 + k];
  }
  #pragma unroll
  for (int o = 32; o > 0; o >>= 1) s += __shfl_down(s, o, 64);
  __shared__ int ws[4];
  if ((t & 63) == 0) ws[t >> 6] = s;
  __syncthreads();
  if (t == 0) bsum[b] = ws[0] + ws[1] + ws[2] + ws[3];
}

// stage 2: exclusive scan of block sums (nb <= 1024), one block of 1024
__global__ void k_scanb(int* __restrict__ bsum, int nb) {
  __shared__ int wsum[16];
  int t = threadIdx.x, lane = t & 63, w = t >> 6;
  int v = (t < nb) ? bsum[t] : 0;
  int x = v;
  #pragma unroll
  for (int o = 1; o < 64; o <<= 1) { int y = __shfl_up(x, o, 64); if (lane >= o) x += y; }
  if (lane == 63) wsum[w] = x;
  __syncthreads();
  int wpre = 0;
  #pragma unroll
  for (int k = 0; k < 16; ++k) if (k < w) wpre += wsum[k];
  int excl = wpre + x - v;
  if (t < nb) bsum[t] = excl;
}

// stage 3: final exclusive offsets, 256 threads per 1024-chunk
__global__ void k_offsets(const int* __restrict__ cnt, int N, const int* __restrict__ bsum,
                          int* __restrict__ off, int E) {
  int b = blockIdx.x;
  int t = threadIdx.x, lane = t & 63, w = t >> 6;
  int i0 = b * 1024 + t * 4;
  int v0 = 0, v1 = 0, v2 = 0, v3 = 0;
  if (i0 + 3 < N) {
    int4 v = *reinterpret_cast<const int4*>(cnt + i0);
    v0 = v.x; v1 = v.y; v2 = v.z; v3 = v.w;
  } else {
    if (i0 + 0 < N) v0 = cnt[i0 + 0];
    if (i0 + 1 < N) v1 = cnt[i0 + 1];
    if (i0 + 2 < N) v2 = cnt[i0 + 2];
    if (i0 + 3 < N) v3 = cnt[i0 + 3];
  }
  int s = v0 + v1 + v2 + v3, x = s;
  #pragma unroll
  for (int o = 1; o < 64; o <<= 1) { int y = __shfl_up(x, o, 64); if (lane >= o) x += y; }
  __shared__ int ws[4];
  if (lane == 63) ws[w] = x;
  __syncthreads();
  int wpre = 0;
  #pragma unroll
  for (int k = 0; k < 4; ++k) if (k < w) wpre += ws[k];
  int excl = bsum[b] + wpre + x - s;
  if (i0 + 0 < N) off[i0 + 0] = excl; excl += v0;
  if (i0 + 1 < N) off[i0 + 1] = excl; excl += v1;
  if (i0 + 2 < N) off[i0 + 2] = excl; excl += v2;
  if (i0 + 3 < N) off[i0 + 3] = excl;
  if (b == 0 && t == 0) off[N] = E;
}

__global__ void k_place(const int* __restrict__ dst, int E, const int* __restrict__ off,
                        int* __restrict__ cur, int* __restrict__ eid) {
  int e = blockIdx.x * 256 + threadIdx.x;
  if (e >= E) return;
  int d = dst[e];
  int p = atomicAdd(&cur[d], 1);
  eid[off[d] + p] = e;
}

// ---------------- weight pre-pack (fp32 W,R -> bf16 MFMA B-fragments) ----------------
// B[cin][col], col<9*Cout: W[k9][cin][cout] (col=k9*Cout+cout); col>=9*Cout: R[cin][col-9*Cout].
// Bp element o = ((kc*CT+ct)*64 + lane)*8 + j holds B[k=kc*32+(lane>>4)*8+j][ct*16+(lane&15)].
template<int Cin, int Cout>
__global__ void k_pack(const float* __restrict__ W, const float* __restrict__ R,
                       __bf16* __restrict__ Bp) {
  constexpr int NC = 10 * Cout;
  constexpr int CT = NC / 16;
  constexpr int KP = (Cin + 31) & ~31;
  int o = blockIdx.x * 256 + threadIdx.x;
  if (o >= KP * NC) return;
  int j = o & 7;
  int lane = (o >> 3) & 63;
  int tile = o >> 9;
  int ct = tile % CT, kc = tile / CT;
  int kg = kc * 32 + ((lane >> 4) * 8) + j;   // = cin (maybe padded)
  int col = ct * 16 + (lane & 15);
  float v = 0.f;
  if (kg < Cin) {
    if (col < 9 * Cout) {
      int k9 = col / Cout, cout = col - k9 * Cout;
      v = W[(k9 * Cin + kg) * Cout + cout];
    } else {
      v = R[kg * Cout + (col - 9 * Cout)];
    }
  }
  Bp[o] = (__bf16)v;
}

// ---------------- Z = X @ B  (MFMA 16x16x32 bf16, fp32 A converted on the fly) --------
template<int Cin, int NC>
__global__ __launch_bounds__(256) void k_zgemm(const float* __restrict__ X,
                        const __bf16* __restrict__ Bp, __bf16* __restrict__ Z, int N) {
  constexpr int KP = (Cin + 31) & ~31;
  constexpr int KC = KP / 32;
  constexpr int CT = NC / 16;
  int lane = threadIdx.x & 63;
  int wave = threadIdx.x >> 6;
  int n0 = blockIdx.x * 64 + wave * 16;
  if (n0 >= N) return;
  int c15 = lane & 15, q = lane >> 4;

  bf16x8 a[KC];
  #pragma unroll
  for (int kc = 0; kc < KC; ++kc) {
    int kofs = kc * 32 + q * 8;
    if (kofs + 8 <= Cin) {
      const float* xr = X + (size_t)(n0 + c15) * Cin + kofs;
      f32x4 lo = *reinterpret_cast<const f32x4*>(xr);
      f32x4 hi = *reinterpret_cast<const f32x4*>(xr + 4);
      #pragma unroll
      for (int t = 0; t < 4; ++t) { a[kc][t] = (__bf16)lo[t]; a[kc][4 + t] = (__bf16)hi[t]; }
    } else {
      #pragma unroll
      for (int t = 0; t < 8; ++t) a[kc][t] = (__bf16)0.0f;
    }
  }

  for (int ct = 0; ct < CT; ++ct) {
    f32x4 acc = {0.f, 0.f, 0.f, 0.f};
    #pragma unroll
    for (int kc = 0; kc < KC; ++kc) {
      bf16x8 b = *reinterpret_cast<const bf16x8*>(Bp + ((size_t)(kc * CT + ct) * 64 + lane) * 8);
      acc = __builtin_amdgcn_mfma_f32_16x16x32_bf16(a[kc], b, acc, 0, 0, 0);
    }
    // C/D layout (m89-verified): col = lane&15, row = (lane>>4)*4 + reg
    __bf16* zb = Z + (size_t)n0 * NC + ct * 16 + c15;
    #pragma unroll
    for (int r = 0; r < 4; ++r) {
      zb[(size_t)(q * 4 + r) * NC] = (__bf16)acc[r];
    }
  }
}

// ------------- edge aggregation (CSR gather) + folded R-term + bias + ReLU -------------
template<int Cout>
__global__ __launch_bounds__(256) void k_econv(const int* __restrict__ src,
                        const float* __restrict__ pseudo,
                        const int* __restrict__ off, const int* __restrict__ eid,
                        const __bf16* __restrict__ Z,
                        const float* __restrict__ bias,
                        float* __restrict__ out, int N, int outStride) {
  constexpr int NC = 10 * Cout;
  int t = blockIdx.x * 256 + threadIdx.x;
  int d = t / Cout;           // Cout is a power of two
  int c = t - d * Cout;
  if (d >= N) return;
  // own-node R-term folded into Z as columns [9*Cout, 10*Cout)
  float acc = (float)Z[(size_t)d * NC + 9 * Cout + c];
  int b0 = off[d], b1 = off[d + 1];
  for (int i = b0; i < b1; ++i) {
    int e = eid[i];
    int s = src[e];
    float t0 = pseudo[2 * (size_t)e + 0];
    float t1 = pseudo[2 * (size_t)e + 1];
    float u0 = 1.f - t0;
    float wi[3] = {0.5f * u0 * u0, -t0 * t0 + t0 + 0.5f, 0.5f * t0 * t0};
    float u1 = 1.f - t1;
    float wj[3] = {0.5f * u1 * u1, -t1 * t1 + t1 + 0.5f, 0.5f * t1 * t1};
    const __bf16* zr = Z + (size_t)s * NC + c;
    float m = 0.f;
    #pragma unroll
    for (int ki = 0; ki < 3; ++ki)
      #pragma unroll
      for (int kj = 0; kj < 3; ++kj)
        m += (wi[ki] * wj[kj]) * (float)zr[(ki * 3 + kj) * Cout];
    acc += m;
  }
  acc += bias[c];
  acc = fmaxf(acc, 0.f);
  out[(size_t)d * outStride + c] = acc;
}

extern "C" void kernel_launch(void* const* d_in, const int* in_sizes, int n_in,
                              void* d_out, int out_size, void* d_ws, size_t ws_size,
                              hipStream_t stream) {
  const float* x0      = (const float*)d_in[0];
  const int*   up1     = (const int*)d_in[1];
  const int*   edge1   = (const int*)d_in[2];
  const float* pseudo1 = (const float*)d_in[3];
  const float* skip1   = (const float*)d_in[4];
  const int*   up2     = (const int*)d_in[5];
  const int*   edge2   = (const int*)d_in[6];
  const float* pseudo2 = (const float*)d_in[7];
  const float* skip2   = (const float*)d_in[8];
  const float* W1a = (const float*)d_in[9];
  const float* R1a = (const float*)d_in[10];
  const float* b1a = (const float*)d_in[11];
  const float* W2a = (const float*)d_in[12];
  const float* R2a = (const float*)d_in[13];
  const float* b2a = (const float*)d_in[14];
  const float* W1b = (const float*)d_in[15];
  const float* R1b = (const float*)d_in[16];
  const float* b1b = (const float*)d_in[17];
  const float* W2b = (const float*)d_in[18];
  const float* R2b = (const float*)d_in[19];
  const float* b2b = (const float*)d_in[20];

  const int N1 = 40000, N2 = 160000, E1 = 240000, E2 = 960000;
  const int NB1 = (N1 + 1023) / 1024;   // 40
  const int NB2 = (N2 + 1023) / 1024;   // 157

  char* ws = (char*)d_ws;
  __bf16* Z   = (__bf16*)(ws);                 // max(N1*320,N2*160)*2 = 51,200,000 B
  float* featA = (float*)(ws + 51200000);      // 20,480,000 B  x1[N1,64] / x2[N2,32]
  float* featB = (float*)(ws + 71680000);      // 20,480,000 B  xcat1[N1,64] / xcat2[N2,32]
  float* featC = (float*)(ws + 92160000);      // 10,240,000 B  x3[N1,32] / x6[N2,16]
  float* featD = (float*)(ws + 102400000);     //  5,120,000 B  h1[N1,32]
  int* off    = (int*)(ws + 107520000);        //  640,004 B (N2+1)
  int* cnt    = (int*)(ws + 108170000);        //  640,000 B
  int* eid    = (int*)(ws + 108810000);        //  3,840,000 B (E2)
  int* bsum   = (int*)(ws + 112650000);        //  1,024 B (<=157 block sums)
  __bf16* BpA = (__bf16*)(ws + 112660000);     //  40,960 B (64x320)
  __bf16* BpB = (__bf16*)(ws + 112700960);     //  20,480 B (32x320)
  __bf16* BpC = (__bf16*)(ws + 112721440);     //  10,240 B (32x160)
  __bf16* BpD = (__bf16*)(ws + 112731680);     //  10,240 B (32x160, K padded from 16)

  // weight packs (tiny)
  k_pack<64, 32><<<80, 256, 0, stream>>>(W1a, R1a, BpA);   // 64*320 = 20480
  k_pack<32, 32><<<40, 256, 0, stream>>>(W2a, R2a, BpB);   // 32*320 = 10240
  k_pack<32, 16><<<20, 256, 0, stream>>>(W1b, R1b, BpC);   // 32*160 = 5120
  k_pack<16, 16><<<20, 256, 0, stream>>>(W2b, R2b, BpD);   // 32*160 = 5120

  // ---------------- level 1 ----------------
  k_unpool<<<(N1 * 16 + 255) / 256, 256, 0, stream>>>((const uint4*)x0, up1, (uint4*)featA, N1, 16);

  hipMemsetAsync(cnt, 0, N1 * 4, stream);
  k_hist<<<(E1 + 255) / 256, 256, 0, stream>>>(edge1 + E1, E1, cnt);
  k_blocksum<<<NB1, 256, 0, stream>>>(cnt, N1, bsum);
  k_scanb<<<1, 1024, 0, stream>>>(bsum, NB1);
  k_offsets<<<NB1, 256, 0, stream>>>(cnt, N1, bsum, off, E1);
  hipMemsetAsync(cnt, 0, N1 * 4, stream);
  k_place<<<(E1 + 255) / 256, 256, 0, stream>>>(edge1 + E1, E1, off, cnt, eid);

  // conv1a: x1(64) -> xcat1[:, :32]
  k_zgemm<64, 320><<<N1 / 64, 256, 0, stream>>>(featA, BpA, Z, N1);
  k_econv<32><<<N1 * 32 / 256, 256, 0, stream>>>(edge1, pseudo1, off, eid, Z, b1a, featB, N1, 64);
  k_skip<<<(N1 * 8 + 255) / 256, 256, 0, stream>>>((const uint4*)skip1, (uint4*)featB, N1, 8, 16, 8);
  // conv2a (reuses W1a,R1a,b1a): xcat1(64) -> x3(32)
  k_zgemm<64, 320><<<N1 / 64, 256, 0, stream>>>(featB, BpA, Z, N1);
  k_econv<32><<<N1 * 32 / 256, 256, 0, stream>>>(edge1, pseudo1, off, eid, Z, b1a, featC, N1, 32);
  // conv3a: x3(32) -> h1(32)
  k_zgemm<32, 320><<<N1 / 64, 256, 0, stream>>>(featC, BpB, Z, N1);
  k_econv<32><<<N1 * 32 / 256, 256, 0, stream>>>(edge1, pseudo1, off, eid, Z, b2a, featD, N1, 32);

  // ---------------- level 2 ----------------
  k_unpool<<<(N2 * 8 + 255) / 256, 256, 0, stream>>>((const uint4*)featD, up2, (uint4*)featA, N2, 8);

  hipMemsetAsync(cnt, 0, N2 * 4, stream);
  k_hist<<<(E2 + 255) / 256, 256, 0, stream>>>(edge2 + E2, E2, cnt);
  k_blocksum<<<NB2, 256, 0, stream>>>(cnt, N2, bsum);
  k_scanb<<<1, 1024, 0, stream>>>(bsum, NB2);
  k_offsets<<<NB2, 256, 0, stream>>>(cnt, N2, bsum, off, E2);
  hipMemsetAsync(cnt, 0, N2 * 4, stream);
  k_place<<<(E2 + 255) / 256, 256, 0, stream>>>(edge2 + E2, E2, off, cnt, eid);

  // conv1b: x2(32) -> xcat2[:, :16]
  k_zgemm<32, 160><<<N2 / 64, 256, 0, stream>>>(featA, BpC, Z, N2);
  k_econv<16><<<N2 * 16 / 256, 256, 0, stream>>>(edge2, pseudo2, off, eid, Z, b1b, featB, N2, 32);
  k_skip<<<(N2 * 4 + 255) / 256, 256, 0, stream>>>((const uint4*)skip2, (uint4*)featB, N2, 4, 8, 4);
  // conv2b (reuses W1b,R1b,b1b): xcat2(32) -> x6(16)
  k_zgemm<32, 160><<<N2 / 64, 256, 0, stream>>>(featB, BpC, Z, N2);
  k_econv<16><<<N2 * 16 / 256, 256, 0, stream>>>(edge2, pseudo2, off, eid, Z, b1b, featC, N2, 16);
  // conv3b: x6(16) -> out(16)
  k_zgemm<16, 160><<<N2 / 64, 256, 0, stream>>>(featC, BpD, Z, N2);
  k_econv<16><<<N2 * 16 / 256, 256, 0, stream>>>(edge2, pseudo2, off, eid, Z, b2b, (float*)d_out, N2, 16);
}